// Round 10
// baseline (1145.277 us; speedup 1.0000x reference)
//
#include <hip/hip_runtime.h>
#include <cstdint>

#define T_TOK 1024
#define HID   2048
#define NEXP  64
#define TOPK  8
#define INTER 768

typedef __attribute__((ext_vector_type(8))) short short8;
typedef __attribute__((ext_vector_type(4))) float f32x4;
typedef __attribute__((ext_vector_type(2))) unsigned int uint2v;

__device__ __forceinline__ unsigned short f2bf(float f){
  unsigned u = __float_as_uint(f);
  u += 0x7FFFu + ((u >> 16) & 1u);   // RNE
  return (unsigned short)(u >> 16);
}

#define LDSA(p) ((unsigned)(uintptr_t)(__attribute__((address_space(3))) void*)(p))
#define TRRD(D, A, IMM) asm volatile("ds_read_b64_tr_b16 %0, %1 offset:" #IMM \
                                     : "=v"(D) : "v"(A))
__device__ __forceinline__ short8 mkfrag(uint2v lo, uint2v hi){
  union { unsigned u[4]; short8 s; } v;
  v.u[0] = lo[0]; v.u[1] = lo[1]; v.u[2] = hi[0]; v.u[3] = hi[1];
  return v.s;
}
#define TRWAIT() do { asm volatile("s_waitcnt lgkmcnt(0)" ::: "memory"); \
                      __builtin_amdgcn_sched_barrier(0); } while (0)
#define BARRIER() do { asm volatile("s_waitcnt lgkmcnt(0)" ::: "memory"); \
                       __builtin_amdgcn_s_barrier(); } while (0)

// ---------------- kernel 1: x (fp32) -> bf16 ----------------
__global__ void k_convert_x(const float* __restrict__ x, unsigned short* __restrict__ xbf){
  int gid = blockIdx.x * 256 + threadIdx.x;
  const float4* src = (const float4*)(x + (size_t)gid * 8);
  float4 a = src[0], b = src[1];
  uint4 p;
  p.x = f2bf(a.x) | ((unsigned)f2bf(a.y) << 16);
  p.y = f2bf(a.z) | ((unsigned)f2bf(a.w) << 16);
  p.z = f2bf(b.x) | ((unsigned)f2bf(b.y) << 16);
  p.w = f2bf(b.z) | ((unsigned)f2bf(b.w) << 16);
  *(uint4*)(xbf + (size_t)gid * 8) = p;
}

// ---------------- kernel 2: router ----------------
__global__ void k_router(const float* __restrict__ x, const float* __restrict__ gw,
                         int* __restrict__ top_idx, float* __restrict__ top_w){
  int t = blockIdx.x;
  int tid = threadIdx.x;
  __shared__ float  xs[HID];
  __shared__ double part[4][NEXP];
  for (int i = tid; i < HID; i += 256) xs[i] = x[(size_t)t * HID + i];
  __syncthreads();
  int e = tid & 63, q = tid >> 6;
  double acc = 0.0;
  const float* gp = gw + e;
  #pragma unroll 8
  for (int h = q * 512; h < q * 512 + 512; ++h)
    acc += (double)xs[h] * (double)gp[(size_t)h * NEXP];
  part[q][e] = acc;
  __syncthreads();
  if (tid < 64){
    float logit = (float)(part[0][e] + part[1][e] + part[2][e] + part[3][e]);
    float cur = logit;
    float vals[TOPK]; int idxs[TOPK];
    #pragma unroll
    for (int k = 0; k < TOPK; ++k){
      float m = cur; int mi = e;
      #pragma unroll
      for (int off = 32; off > 0; off >>= 1){
        float ov = __shfl_xor(m, off);
        int   oi = __shfl_xor(mi, off);
        if (ov > m || (ov == m && oi < mi)){ m = ov; mi = oi; }
      }
      vals[k] = m; idxs[k] = mi;
      if (e == mi) cur = -1e30f;
    }
    float mx = vals[0], s = 0.f, ev[TOPK];
    #pragma unroll
    for (int k = 0; k < TOPK; ++k){ ev[k] = expf(vals[k] - mx); s += ev[k]; }
    #pragma unroll
    for (int k = 0; k < TOPK; ++k)
      if (e == k){ top_idx[t * TOPK + k] = idxs[k]; top_w[t * TOPK + k] = ev[k] / s; }
  }
}

// ---------------- kernel 3: histogram + scan ----------------
__global__ void k_hist(const int* __restrict__ top_idx, int* __restrict__ offs){
  __shared__ int hist[NEXP];
  int tid = threadIdx.x;
  if (tid < NEXP) hist[tid] = 0;
  __syncthreads();
  for (int j = tid; j < T_TOK * TOPK; j += 256) atomicAdd(&hist[top_idx[j]], 1);
  __syncthreads();
  if (tid == 0){
    int run = 0;
    for (int e = 0; e < NEXP; ++e){ offs[e] = run; run += hist[e]; }
    offs[NEXP] = run;
  }
}

// ---------------- kernel 4: ordered compaction ----------------
__global__ void k_compact(const int* __restrict__ top_idx, const float* __restrict__ top_w,
                          const int* __restrict__ offs, int* __restrict__ list_t,
                          float* __restrict__ list_w, int* __restrict__ slot_of){
  int e = blockIdx.x, tid = threadIdx.x;
  __shared__ int sc[256];
  int j0 = tid * 32, cnt = 0;
  for (int jj = 0; jj < 32; ++jj) cnt += (top_idx[j0 + jj] == e);
  sc[tid] = cnt; __syncthreads();
  for (int d = 1; d < 256; d <<= 1){
    int v = (tid >= d) ? sc[tid - d] : 0;
    __syncthreads();
    sc[tid] += v;
    __syncthreads();
  }
  int pos = offs[e] + sc[tid] - cnt;
  for (int jj = 0; jj < 32; ++jj){
    int j = j0 + jj;
    if (top_idx[j] == e){
      list_t[pos]  = j >> 3;
      list_w[pos]  = top_w[j];
      slot_of[j]   = pos;
      ++pos;
    }
  }
}

// ---------------- kernel 5: gate/up row-streaming GEMM ----------------
// Block = (expert, mat in {gate,up}, col-half of 384, m-chunk of 48). 512 thr, 8 waves.
// Each wave stages 4 FULL consecutive rows (1.5 KB contiguous each) per BK=32 tile;
// waves split N=384 into 48-col slices (3 panels each). Ring-3 LDS, raw barriers,
// compiler-counted vmcnt (B tau+2 / A tau+1 in flight). Writes fp32 g/u (no SwiGLU here).
__global__ __launch_bounds__(512, 1) void k_gu(
    const unsigned short* __restrict__ xbf, const float* __restrict__ wg,
    const float* __restrict__ wu, const int* __restrict__ offs,
    const int* __restrict__ list_t, float* __restrict__ gbuf, float* __restrict__ ubuf){
  int bid = blockIdx.x;                   // 1024
  int xcd = bid & 7, idx = bid >> 3;      // idx 0..127
  int combo = (idx >> 2) * 8 + xcd;       // 0..255: same combo's 4 m-chunks adjacent/XCD
  int mchunk = idx & 3;
  int e = combo >> 2, mat = (combo >> 1) & 1, half = combo & 1;
  int beg = offs[e], n_e = offs[e + 1] - beg;
  int tid = threadIdx.x, lane = tid & 63, w = tid >> 6;
  int cL = lane & 15, qL = lane >> 4;

  __shared__ unsigned short lB[3][24 * 512];   // ring-3 x 24 KB ([panel][32k][16c])
  const float* W = (mat ? wu : wg) + (size_t)e * HID * INTER + half * 384;
  float* obuf = (mat ? ubuf : gbuf) + half * 384;

  int srow = 4 * w + qL;                       // staged row within tile (0..31)
  const float* sBase = W + (size_t)srow * INTER + cL * 24;
  int wOffS[6];
  #pragma unroll
  for (int g = 0; g < 6; ++g){
    int c = cL * 24 + 4 * g;
    wOffS[g] = (c >> 4) * 512 + srow * 16 + (c & 15);
  }
  unsigned rdB = LDSA(&lB[0][0]) + (unsigned)(3 * w) * 1024 + (unsigned)lane * 8;

#define GU_LB(T, S) { \
    const float* _p = sBase + (size_t)(T) * 32 * INTER; \
    _Pragma("unroll") for (int j = 0; j < 6; ++j) bs[S][j] = *(const float4*)(_p + 4 * j); }

#define GU_LA(T, S) { \
    _Pragma("unroll") for (int mf = 0; mf < 3; ++mf){ \
      const unsigned short* _ap = aP[mf] + (T) * 32 + 4 * qL; \
      ra[S][mf] = mkfrag(*(const uint2v*)_ap, *(const uint2v*)(_ap + 16)); } }

#define GU_WB(BUF, S) { \
    _Pragma("unroll") for (int g = 0; g < 6; ++g){ \
      uint2v _v; \
      _v[0] = (unsigned)f2bf(bs[S][g].x) | ((unsigned)f2bf(bs[S][g].y) << 16); \
      _v[1] = (unsigned)f2bf(bs[S][g].z) | ((unsigned)f2bf(bs[S][g].w) << 16); \
      *(uint2v*)(&lB[BUF][0] + wOffS[g]) = _v; } }

#define GU_MM(BUF, S) { \
    unsigned _b = rdB + (BUF) * 24576; \
    uint2v _l0,_h0,_l1,_h1,_l2,_h2; \
    TRRD(_l0, _b, 0);    TRRD(_h0, _b, 512); \
    TRRD(_l1, _b, 1024); TRRD(_h1, _b, 1536); \
    TRRD(_l2, _b, 2048); TRRD(_h2, _b, 2560); \
    TRWAIT(); \
    short8 _f0 = mkfrag(_l0,_h0), _f1 = mkfrag(_l1,_h1), _f2 = mkfrag(_l2,_h2); \
    _Pragma("unroll") for (int mf = 0; mf < 3; ++mf){ \
      acc[mf][0] = __builtin_amdgcn_mfma_f32_16x16x32_bf16(ra[S][mf], _f0, acc[mf][0], 0, 0, 0); \
      acc[mf][1] = __builtin_amdgcn_mfma_f32_16x16x32_bf16(ra[S][mf], _f1, acc[mf][1], 0, 0, 0); \
      acc[mf][2] = __builtin_amdgcn_mfma_f32_16x16x32_bf16(ra[S][mf], _f2, acc[mf][2], 0, 0, 0); } }

// K = T mod 6 (compile-time): avoids runtime-indexed reg arrays (scratch hazard).
#define GU_BODY(T, K, DA, DB, DW) { \
    if (DA) GU_LA((T) + 1, ((K) + 1) & 1); \
    if (DB) GU_LB((T) + 2, (K) & 1); \
    GU_MM((K) % 3, (K) & 1); \
    if (DW) GU_WB(((K) + 1) % 3, ((K) + 1) & 1); \
    BARRIER(); }

  for (int m0 = mchunk * 48; m0 < n_e; m0 += 192){
    const unsigned short* aP[3];
    #pragma unroll
    for (int mf = 0; mf < 3; ++mf){
      int r = m0 + mf * 16 + cL;
      int tok = list_t[(r < n_e) ? (beg + r) : beg];
      aP[mf] = xbf + (size_t)tok * HID;
    }
    float4 bs[2][6];
    short8 ra[2][3];
    f32x4 acc[3][3] = {};

    GU_LA(0, 0);
    GU_LB(0, 0);
    GU_LB(1, 1);
    GU_WB(0, 0);                  // drains A0+B0; B1 stays in flight
    BARRIER();

    #pragma unroll 1
    for (int t = 0; t < 60; t += 6){
      GU_BODY(t + 0, 0, 1, 1, 1); GU_BODY(t + 1, 1, 1, 1, 1);
      GU_BODY(t + 2, 2, 1, 1, 1); GU_BODY(t + 3, 3, 1, 1, 1);
      GU_BODY(t + 4, 4, 1, 1, 1); GU_BODY(t + 5, 5, 1, 1, 1);
    }
    GU_BODY(60, 0, 1, 1, 1);
    GU_BODY(61, 1, 1, 1, 1);      // issues B(63) last
    GU_BODY(62, 2, 1, 0, 1);      // A(63) last, writes B(63)
    GU_MM(0, 1);                  // body 63 (63%3=0, 63&1=1)
    BARRIER();

    #pragma unroll
    for (int mf = 0; mf < 3; ++mf){
      #pragma unroll
      for (int rr = 0; rr < 4; ++rr){
        int r = m0 + mf * 16 + qL * 4 + rr;
        if (r < n_e){
          size_t ro = (size_t)(beg + r) * INTER;
          #pragma unroll
          for (int j = 0; j < 3; ++j)
            obuf[ro + w * 48 + j * 16 + cL] = acc[mf][j][rr];
        }
      }
    }
  }
}

// ---------------- kernel 6: SwiGLU + routing weight -> bf16 act ----------------
__global__ void k_swiglu(const float* __restrict__ gbuf, const float* __restrict__ ubuf,
                         const float* __restrict__ list_w, unsigned short* __restrict__ act){
  #pragma unroll
  for (int i = 0; i < 3; ++i){
    int idx = blockIdx.x * 768 + i * 256 + threadIdx.x;   // 2048 blocks -> 1572864 float4s
    float4 g = ((const float4*)gbuf)[idx];
    float4 u = ((const float4*)ubuf)[idx];
    float wgt = list_w[idx / 192];
    float h0 = (g.x / (1.f + expf(-g.x))) * u.x * wgt;
    float h1 = (g.y / (1.f + expf(-g.y))) * u.y * wgt;
    float h2 = (g.z / (1.f + expf(-g.z))) * u.z * wgt;
    float h3 = (g.w / (1.f + expf(-g.w))) * u.w * wgt;
    uint2v p;
    p[0] = (unsigned)f2bf(h0) | ((unsigned)f2bf(h1) << 16);
    p[1] = (unsigned)f2bf(h2) | ((unsigned)f2bf(h3) << 16);
    *(uint2v*)(act + (size_t)idx * 4) = p;
  }
}

// ---------------- kernel 7: down-proj row-streaming GEMM ----------------
// Block = (expert, col-quarter of 512, m-chunk of 48). Waves stage 4 full
// 2-KB quarter-rows each; waves split N=512 into 64-col slices (4 panels).
__global__ __launch_bounds__(512, 1) void k_dn(
    const unsigned short* __restrict__ act, const float* __restrict__ wd,
    const int* __restrict__ offs, const int* __restrict__ list_t,
    float* __restrict__ contrib, float* __restrict__ out, int atomicMode){
  int bid = blockIdx.x;                   // 1024
  int xcd = bid & 7, idx = bid >> 3;
  int combo = (idx >> 2) * 8 + xcd;       // 0..255
  int mchunk = idx & 3;
  int e = combo >> 2, nq = combo & 3;
  int beg = offs[e], n_e = offs[e + 1] - beg;
  int tid = threadIdx.x, lane = tid & 63, w = tid >> 6;
  int cL = lane & 15, qL = lane >> 4;

  __shared__ unsigned short lB[3][32 * 512];   // ring-3 x 32 KB
  const float* W = wd + (size_t)e * INTER * HID + nq * 512;

  int srow = 4 * w + qL;
  const float* sBase = W + (size_t)srow * HID + cL * 32;
  int wOffS[8];
  #pragma unroll
  for (int g = 0; g < 8; ++g){
    int c = cL * 32 + 4 * g;
    wOffS[g] = (c >> 4) * 512 + srow * 16 + (c & 15);
  }
  unsigned rdB = LDSA(&lB[0][0]) + (unsigned)(4 * w) * 1024 + (unsigned)lane * 8;

#define DN_LB(T, S) { \
    const float* _p = sBase + (size_t)(T) * 32 * HID; \
    _Pragma("unroll") for (int j = 0; j < 8; ++j) bs[S][j] = *(const float4*)(_p + 4 * j); }

#define DN_LA(T, S) { \
    _Pragma("unroll") for (int mf = 0; mf < 3; ++mf){ \
      const unsigned short* _ap = aP[mf] + (T) * 32 + 4 * qL; \
      ra[S][mf] = mkfrag(*(const uint2v*)_ap, *(const uint2v*)(_ap + 16)); } }

#define DN_WB(BUF, S) { \
    _Pragma("unroll") for (int g = 0; g < 8; ++g){ \
      uint2v _v; \
      _v[0] = (unsigned)f2bf(bs[S][g].x) | ((unsigned)f2bf(bs[S][g].y) << 16); \
      _v[1] = (unsigned)f2bf(bs[S][g].z) | ((unsigned)f2bf(bs[S][g].w) << 16); \
      *(uint2v*)(&lB[BUF][0] + wOffS[g]) = _v; } }

#define DN_MM(BUF, S) { \
    unsigned _b = rdB + (BUF) * 32768; \
    uint2v _l0,_h0,_l1,_h1,_l2,_h2,_l3,_h3; \
    TRRD(_l0, _b, 0);    TRRD(_h0, _b, 512); \
    TRRD(_l1, _b, 1024); TRRD(_h1, _b, 1536); \
    TRRD(_l2, _b, 2048); TRRD(_h2, _b, 2560); \
    TRRD(_l3, _b, 3072); TRRD(_h3, _b, 3584); \
    TRWAIT(); \
    short8 _f0 = mkfrag(_l0,_h0), _f1 = mkfrag(_l1,_h1); \
    short8 _f2 = mkfrag(_l2,_h2), _f3 = mkfrag(_l3,_h3); \
    _Pragma("unroll") for (int mf = 0; mf < 3; ++mf){ \
      acc[mf][0] = __builtin_amdgcn_mfma_f32_16x16x32_bf16(ra[S][mf], _f0, acc[mf][0], 0, 0, 0); \
      acc[mf][1] = __builtin_amdgcn_mfma_f32_16x16x32_bf16(ra[S][mf], _f1, acc[mf][1], 0, 0, 0); \
      acc[mf][2] = __builtin_amdgcn_mfma_f32_16x16x32_bf16(ra[S][mf], _f2, acc[mf][2], 0, 0, 0); \
      acc[mf][3] = __builtin_amdgcn_mfma_f32_16x16x32_bf16(ra[S][mf], _f3, acc[mf][3], 0, 0, 0); } }

#define DN_BODY(T, K, DA, DB, DW) { \
    if (DA) DN_LA((T) + 1, ((K) + 1) & 1); \
    if (DB) DN_LB((T) + 2, (K) & 1); \
    DN_MM((K) % 3, (K) & 1); \
    if (DW) DN_WB(((K) + 1) % 3, ((K) + 1) & 1); \
    BARRIER(); }

  for (int m0 = mchunk * 48; m0 < n_e; m0 += 192){
    const unsigned short* aP[3];
    #pragma unroll
    for (int mf = 0; mf < 3; ++mf){
      int r = m0 + mf * 16 + cL;
      aP[mf] = act + (size_t)((r < n_e) ? (beg + r) : beg) * INTER;
    }
    float4 bs[2][8];
    short8 ra[2][3];
    f32x4 acc[3][4] = {};

    DN_LA(0, 0);
    DN_LB(0, 0);
    DN_LB(1, 1);
    DN_WB(0, 0);
    BARRIER();

    #pragma unroll 1
    for (int t = 0; t < 18; t += 6){
      DN_BODY(t + 0, 0, 1, 1, 1); DN_BODY(t + 1, 1, 1, 1, 1);
      DN_BODY(t + 2, 2, 1, 1, 1); DN_BODY(t + 3, 3, 1, 1, 1);
      DN_BODY(t + 4, 4, 1, 1, 1); DN_BODY(t + 5, 5, 1, 1, 1);
    }
    DN_BODY(18, 0, 1, 1, 1);
    DN_BODY(19, 1, 1, 1, 1);
    DN_BODY(20, 2, 1, 1, 1);
    DN_BODY(21, 3, 1, 1, 1);      // issues B(23) last
    DN_BODY(22, 4, 1, 0, 1);      // A(23) last, writes B(23)
    DN_MM(2, 1);                  // body 23 (23%3=2, 23&1=1)
    BARRIER();

    #pragma unroll
    for (int mf = 0; mf < 3; ++mf){
      #pragma unroll
      for (int rr = 0; rr < 4; ++rr){
        int r = m0 + mf * 16 + qL * 4 + rr;
        if (r < n_e){
          int slot = beg + r;
          #pragma unroll
          for (int j = 0; j < 4; ++j){
            float v = acc[mf][j][rr];
            int h = nq * 512 + w * 64 + j * 16 + cL;
            if (atomicMode) atomicAdd(&out[(size_t)list_t[slot] * HID + h], v);
            else            contrib[(size_t)slot * HID + h] = v;
          }
        }
      }
    }
  }
}

// ---------------- kernel 8: deterministic 8-way combine ----------------
__global__ void k_reduce(const float* __restrict__ contrib, const int* __restrict__ slot_of,
                         float* __restrict__ out){
  int bx = blockIdx.x;
  int t = bx >> 1, seg = bx & 1, tid = threadIdx.x;
  __shared__ int ss[TOPK];
  if (tid < TOPK) ss[tid] = slot_of[t * TOPK + tid];
  __syncthreads();
  int h = (seg * 256 + tid) * 4;
  f32x4 s = {0.f, 0.f, 0.f, 0.f};
  #pragma unroll
  for (int k = 0; k < TOPK; ++k){
    f32x4 v = *(const f32x4*)(contrib + (size_t)ss[k] * HID + h);
    s += v;
  }
  *(f32x4*)(out + (size_t)t * HID + h) = s;
}

extern "C" void kernel_launch(void* const* d_in, const int* in_sizes, int n_in,
                              void* d_out, int out_size, void* d_ws, size_t ws_size,
                              hipStream_t stream){
  const float* x   = (const float*)d_in[0];
  const float* gw  = (const float*)d_in[1];
  const float* wgp = (const float*)d_in[2];
  const float* wup = (const float*)d_in[3];
  const float* wdp = (const float*)d_in[4];
  float* out = (float*)d_out;
  char* ws = (char*)d_ws;

  int*   top_idx = (int*)  (ws + 0);
  float* top_w   = (float*)(ws + 32768);
  int*   offs    = (int*)  (ws + 65536);
  int*   list_t  = (int*)  (ws + 69632);
  float* list_w  = (float*)(ws + 102400);
  int*   slot_of = (int*)  (ws + 135168);
  unsigned short* xbf = (unsigned short*)(ws + 167936);             // 4 MB
  unsigned short* act = (unsigned short*)(ws + 167936 + 4194304);   // 12 MB
  char* big = ws + 167936 + 4194304 + 12582912;
  float* gbuf    = (float*)big;                    // 25.2 MB  (aliases contrib)
  float* ubuf    = (float*)(big + 25165824);       // 25.2 MB  (aliases contrib)
  float* contrib = (float*)big;                    // 67.1 MB  (after swiglu)
  size_t need_full = (size_t)167936 + 4194304 + 12582912 + 67108864;
  int atomicMode = (ws_size < need_full) ? 1 : 0;

  k_convert_x<<<1024, 256, 0, stream>>>(x, xbf);
  k_router   <<<1024, 256, 0, stream>>>(x, gw, top_idx, top_w);
  k_hist     <<<1,    256, 0, stream>>>(top_idx, offs);
  k_compact  <<<64,   256, 0, stream>>>(top_idx, top_w, offs, list_t, list_w, slot_of);
  k_gu       <<<1024, 512, 0, stream>>>(xbf, wgp, wup, offs, list_t, gbuf, ubuf);
  k_swiglu   <<<2048, 256, 0, stream>>>(gbuf, ubuf, list_w, act);
  if (atomicMode){
    hipMemsetAsync(d_out, 0, (size_t)out_size * sizeof(float), stream);
    k_dn    <<<1024, 512, 0, stream>>>(act, wdp, offs, list_t, contrib, out, 1);
  } else {
    k_dn    <<<1024, 512, 0, stream>>>(act, wdp, offs, list_t, contrib, out, 0);
    k_reduce<<<2048, 256, 0, stream>>>(contrib, slot_of, out);
  }
}